// Round 4
// baseline (442.039 us; speedup 1.0000x reference)
//
#include <hip/hip_runtime.h>
#include <hip/hip_bf16.h>

typedef unsigned char u8;
typedef unsigned short u16;
typedef unsigned int u32;
typedef __attribute__((ext_vector_type(4))) int intx4;
typedef __attribute__((ext_vector_type(8))) int intx8;
typedef __attribute__((ext_vector_type(4))) float floatx4;

#define NPIX 12544   // 112*112 = 98 * 128
#define KDIM 768     // channels; fp8 row = 768 B
#define EPSF 1e-8f
#define SCALE1 0x7F7F7F7FU  // E8M0 = 127 -> 2^0 = 1.0 in every byte

// ---------------------------------------------------------------- async G->LDS
__device__ __forceinline__ void gload_lds16(const void* g, void* l) {
  __builtin_amdgcn_global_load_lds(
      (const __attribute__((address_space(1))) void*)g,
      (__attribute__((address_space(3))) void*)l, 16, 0, 0);
}

// sortable-uint encoding of float (monotone): max over enc == max over float
__device__ __forceinline__ u32 enc_f32(float f) {
  u32 u = __float_as_uint(f);
  return (u & 0x80000000u) ? ~u : (u | 0x80000000u);
}
__device__ __forceinline__ float dec_f32(u32 e) {
  u32 u = (e & 0x80000000u) ? (e & 0x7FFFFFFFu) : ~e;
  return __uint_as_float(u);
}

// ---------------------------------------------------------------- K1: column sum-of-squares partials
// grid (49, 8), block 256. pa/pb: [8][NPIX]
__global__ void colsumsq_kernel(const float* __restrict__ a, const float* __restrict__ b,
                                float* __restrict__ pa, float* __restrict__ pb) {
  int i = blockIdx.x * 256 + threadIdx.x;
  int c0 = blockIdx.y * 96;
  float sa = 0.f, sb = 0.f;
#pragma unroll 4
  for (int c = c0; c < c0 + 96; ++c) {
    float va = a[(size_t)c * NPIX + i];
    float vb = b[(size_t)c * NPIX + i];
    sa += va * va;
    sb += vb * vb;
  }
  pa[(size_t)blockIdx.y * NPIX + i] = sa;
  pb[(size_t)blockIdx.y * NPIX + i] = sb;
}

// ---------------------------------------------------------------- K2: 1/(sqrt(sum+eps)+eps) + zero atomic-max buffer
// grid 49, block 256
__global__ void rnorm_kernel(const float* __restrict__ pa, const float* __restrict__ pb,
                             float* __restrict__ ra, float* __restrict__ rb,
                             u32* __restrict__ part) {
  int i = blockIdx.x * 256 + threadIdx.x;
  float sa = 0.f, sb = 0.f;
#pragma unroll
  for (int c = 0; c < 8; ++c) {
    sa += pa[(size_t)c * NPIX + i];
    sb += pb[(size_t)c * NPIX + i];
  }
  ra[i] = 1.f / (sqrtf(sa + EPSF) + EPSF);
  rb[i] = 1.f / (sqrtf(sb + EPSF) + EPSF);
  part[i] = 0u;  // encoded floor (< enc of any finite float)
}

// ---------------------------------------------------------------- K3: transpose + normalize + fp8 e4m3 pack
// (C,N) f32 -> (N,C) fp8.  grid (392, 24, 2), block 256
// stage: 32x32 f32 tile in LDS; emit: each thread packs 4 consecutive channels
// of one pixel into a u32 (v_cvt_pk_fp8_f32 x2), coalesced 4B/lane stores.
__global__ void transpose_kernel(const float* __restrict__ a, const float* __restrict__ b,
                                 const float* __restrict__ ra, const float* __restrict__ rb,
                                 u8* __restrict__ Ar, u8* __restrict__ Br) {
  const float* src = blockIdx.z ? b : a;
  const float* rn  = blockIdx.z ? rb : ra;
  u8* dst          = blockIdx.z ? Br : Ar;
  __shared__ float tile[32][33];
  int i0 = blockIdx.x * 32;
  int c0 = blockIdx.y * 32;
  int tx = threadIdx.x & 31;
  int ty = threadIdx.x >> 5;  // 0..7
#pragma unroll
  for (int d = 0; d < 4; ++d) {
    int c = c0 + ty + d * 8;
    tile[ty + d * 8][tx] = src[(size_t)c * NPIX + i0 + tx];
  }
  __syncthreads();
  int pl = threadIdx.x >> 3;        // pixel-local 0..31
  int cq = threadIdx.x & 7;         // channel-quad 0..7
  int gi = i0 + pl;
  float r = rn[gi];
  float v0 = tile[cq * 4 + 0][pl] * r;
  float v1 = tile[cq * 4 + 1][pl] * r;
  float v2 = tile[cq * 4 + 2][pl] * r;
  float v3 = tile[cq * 4 + 3][pl] * r;
  int p = __builtin_amdgcn_cvt_pk_fp8_f32(v0, v1, 0, false);
  p = __builtin_amdgcn_cvt_pk_fp8_f32(v2, v3, p, true);
  *(u32*)&dst[(size_t)gi * KDIM + c0 + cq * 4] = (u32)p;
}

// ---------------------------------------------------------------- K4: one 128x128 tile per block, MX-fp8 K=128
// grid (8, 13, 98): x = XCD chunk (13 col tiles for x<2, 12 for x>=2), y = tile
// in chunk, z = row tile. linear%8==x -> per-XCD B panel (~1.2 MB) L2-pinned.
// LDS layout: row r (128 B) split in 8x16B chunks; logical chunk c at physical
// slot c ^ (r&7)  -> balanced banks for both staging and ds_read_b128.
__global__ __launch_bounds__(256) void gemm_max_kernel(const u8* __restrict__ Ar,
                                                       const u8* __restrict__ Br,
                                                       u32* __restrict__ part) {
  const int X = blockIdx.x;
  const int t13 = blockIdx.y;
  const int live = (X < 2) ? 13 : 12;
  if (t13 >= live) return;
  const int ct = (X < 2) ? (X * 13 + t13) : (X * 12 + 2 + t13);
  const int rt = blockIdx.z;

  __shared__ alignas(16) u8 As[128 * 128];
  __shared__ alignas(16) u8 Bs[128 * 128];
  __shared__ float s_max[2 * 128];

  const int tid = threadIdx.x;
  const int wave = tid >> 6;
  const int lane = tid & 63;
  const int wx = wave & 1;
  const int wy = wave >> 1;
  const int l15 = lane & 15;
  const int quad = lane >> 4;

  const int row_base = rt * 128;
  const int col_base = ct * 128;

  // staging map: thread tid -> LDS byte tid*16 (+j*4096) == (row j*32 + tid>>3,
  // slot tid&7); source logical chunk c = slot ^ (row&7) = (tid&7)^((tid>>3)&7)
  const int sr = tid >> 3;                      // 0..31
  const int c  = (tid & 7) ^ (sr & 7);          // j-invariant
  const u8* gA = Ar + (size_t)(row_base + sr) * KDIM + c * 16;
  const u8* gB = Br + (size_t)(col_base + sr) * KDIM + c * 16;
  u8* lA = &As[tid * 16];
  u8* lB = &Bs[tid * 16];

  floatx4 acc[4][4];
#pragma unroll
  for (int mf = 0; mf < 4; ++mf)
#pragma unroll
    for (int nf = 0; nf < 4; ++nf) acc[mf][nf] = (floatx4){0.f, 0.f, 0.f, 0.f};

  for (int k0 = 0; k0 < KDIM; k0 += 128) {
    __syncthreads();  // previous step's LDS reads done
#pragma unroll
    for (int j = 0; j < 4; ++j) {
      gload_lds16(gA + (size_t)(j * 32) * KDIM + k0, lA + j * 4096);
      gload_lds16(gB + (size_t)(j * 32) * KDIM + k0, lB + j * 4096);
    }
    __syncthreads();  // staging drained

    intx8 bfr[4];
#pragma unroll
    for (int nf = 0; nf < 4; ++nf) {
      const int Rb = wx * 64 + nf * 16 + l15;
      const int p0 = (2 * quad) ^ (Rb & 7);
      const int base = Rb * 128;
      intx4 lo = *(const intx4*)&Bs[base + p0 * 16];
      intx4 hi = *(const intx4*)&Bs[base + (p0 ^ 1) * 16];
      intx8 f;
      f[0] = lo[0]; f[1] = lo[1]; f[2] = lo[2]; f[3] = lo[3];
      f[4] = hi[0]; f[5] = hi[1]; f[6] = hi[2]; f[7] = hi[3];
      bfr[nf] = f;
    }
#pragma unroll
    for (int mf = 0; mf < 4; ++mf) {
      const int Ra = wy * 64 + mf * 16 + l15;
      const int p0 = (2 * quad) ^ (Ra & 7);
      const int base = Ra * 128;
      intx4 lo = *(const intx4*)&As[base + p0 * 16];
      intx4 hi = *(const intx4*)&As[base + (p0 ^ 1) * 16];
      intx8 afr;
      afr[0] = lo[0]; afr[1] = lo[1]; afr[2] = lo[2]; afr[3] = lo[3];
      afr[4] = hi[0]; afr[5] = hi[1]; afr[6] = hi[2]; afr[7] = hi[3];
#pragma unroll
      for (int nf = 0; nf < 4; ++nf)
        acc[mf][nf] = __builtin_amdgcn_mfma_scale_f32_16x16x128_f8f6f4(
            afr, bfr[nf], acc[mf][nf], 0, 0, 0, SCALE1, 0, SCALE1);
    }
  }

  // epilogue: per-row max over the 128-col tile.
  // C layout (shape-determined): col = l15 (+nf*16), row = quad*4 + r (+mf*16)
#pragma unroll
  for (int mf = 0; mf < 4; ++mf) {
#pragma unroll
    for (int r = 0; r < 4; ++r) {
      float best = acc[mf][0][r];
      best = fmaxf(best, acc[mf][1][r]);
      best = fmaxf(best, acc[mf][2][r]);
      best = fmaxf(best, acc[mf][3][r]);
      best = fmaxf(best, __shfl_xor(best, 1));
      best = fmaxf(best, __shfl_xor(best, 2));
      best = fmaxf(best, __shfl_xor(best, 4));
      best = fmaxf(best, __shfl_xor(best, 8));
      if (l15 == 0) {
        int row = wy * 64 + mf * 16 + quad * 4 + r;
        s_max[wx * 128 + row] = best;
      }
    }
  }
  __syncthreads();
  if (tid < 128) {
    float m = fmaxf(s_max[tid], s_max[128 + tid]);
    atomicMax(&part[row_base + tid], enc_f32(m));
  }
}

// ---------------------------------------------------------------- K5: decode + loss (fp32 scalar out)
__global__ void finish_kernel(const u32* __restrict__ part, float* __restrict__ out) {
  float v = 0.f;
  for (int i = threadIdx.x; i < NPIX; i += 1024) {
    v += 1.0f - dec_f32(part[i]);
  }
#pragma unroll
  for (int off = 32; off > 0; off >>= 1) v += __shfl_down(v, off);
  __shared__ float red[16];
  int w = threadIdx.x >> 6;
  if ((threadIdx.x & 63) == 0) red[w] = v;
  __syncthreads();
  if (threadIdx.x == 0) {
    float s = 0.f;
#pragma unroll
    for (int k = 0; k < 16; ++k) s += red[k];
    out[0] = s * (1.0f / (float)NPIX);
  }
}

// ---------------------------------------------------------------- launcher
extern "C" void kernel_launch(void* const* d_in, const int* in_sizes, int n_in,
                              void* d_out, int out_size, void* d_ws, size_t ws_size,
                              hipStream_t stream) {
  const float* x = (const float*)d_in[0];
  const float* s = (const float*)d_in[1];
  char* ws = (char*)d_ws;
  float* pa   = (float*)(ws + 0);         //   401408
  float* pb   = (float*)(ws + 401408);    //   401408
  float* ra   = (float*)(ws + 802816);    //    50176
  float* rb   = (float*)(ws + 852992);    //    50176
  u32*   part = (u32*)  (ws + 903168);    //    50176 (encoded row maxima)
  u8*    Ar   = (u8*)   (ws + 953344);    //  9633792
  u8*    Br   = (u8*)   (ws + 10587136);  //  9633792  -> total 20220928 B

  colsumsq_kernel<<<dim3(49, 8), 256, 0, stream>>>(x, s, pa, pb);
  rnorm_kernel<<<49, 256, 0, stream>>>(pa, pb, ra, rb, part);
  transpose_kernel<<<dim3(392, 24, 2), 256, 0, stream>>>(x, s, ra, rb, Ar, Br);
  gemm_max_kernel<<<dim3(8, 13, 98), 256, 0, stream>>>(Ar, Br, part);
  finish_kernel<<<1, 1024, 0, stream>>>(part, (float*)d_out);
}